// Round 1
// baseline (639.877 us; speedup 1.0000x reference)
//
#include <hip/hip_runtime.h>

// DECOLLE SNN forward, MI355X f32 baseline.
// B=32, F_IN=512, H=1024, OUT=128, T=256.
// d_out layout (floats): s1[8388608] s2[8388608] r1[1048576] r2[1048576]
//                        v1[8388608] v2[8388608] c1[1] c2[1]
// z1/z2 are staged in the v1/v2 slots and overwritten in place by the scan.

#define S_SZ 8388608
#define R_SZ 1048576

// ---------------- zero r1/r2 region + ws counters ----------------
__global__ __launch_bounds__(256) void zero_r_kernel(float* __restrict__ r,
                                                     int* __restrict__ cnt) {
  int i = blockIdx.x * 256 + threadIdx.x;
  float4 z{0.f, 0.f, 0.f, 0.f};
  *(float4*)&r[(size_t)i * 4] = z;
  if (i == 0) { cnt[0] = 0; cnt[1] = 0; }
}

// ---------------- batched GEMM: Z[b,m,t] = sum_k W[m,k] * X[b,k,t] ----------
// Tile: 128 (m) x 64 (t), K-chunk 16, 256 threads, 8x4 micro-tile.
__global__ __launch_bounds__(256) void gemm_f32(
    const float* __restrict__ W, const float* __restrict__ X,
    float* __restrict__ Z, int M, int K) {
  const int T = 256;
  const int tt0 = blockIdx.x * 64;
  const int m0  = blockIdx.y * 128;
  const int b   = blockIdx.z;
  const float* __restrict__ Xb = X + (size_t)b * K * T;
  float* __restrict__ Zb = Z + (size_t)b * M * T;

  __shared__ float Ws[16][132];  // [k][m] transposed, padded
  __shared__ float Xs[16][68];   // [k][t], padded (keeps 16B alignment)

  const int tid = threadIdx.x;
  const int tx = tid & 15;   // t group (4 t each)
  const int ty = tid >> 4;   // m group (8 m each)

  const int ah  = tid >> 1;        // W row 0..127
  const int ac  = (tid & 1) * 8;   // W col sub-offset 0 or 8
  const int bf  = tid >> 4;        // X k row 0..15
  const int btq = (tid & 15) * 4;  // X t offset

  float acc[8][4];
#pragma unroll
  for (int i = 0; i < 8; ++i)
#pragma unroll
    for (int j = 0; j < 4; ++j) acc[i][j] = 0.f;

  const float* wp = &W[(size_t)(m0 + ah) * K + ac];
  const float* xp = &Xb[(size_t)bf * T + tt0 + btq];

  for (int k0 = 0; k0 < K; k0 += 16) {
    float4 wa0 = *(const float4*)(wp + k0);
    float4 wa1 = *(const float4*)(wp + k0 + 4);
    float4 xv  = *(const float4*)(xp + (size_t)k0 * T);
    __syncthreads();
    Ws[ac + 0][ah] = wa0.x; Ws[ac + 1][ah] = wa0.y;
    Ws[ac + 2][ah] = wa0.z; Ws[ac + 3][ah] = wa0.w;
    Ws[ac + 4][ah] = wa1.x; Ws[ac + 5][ah] = wa1.y;
    Ws[ac + 6][ah] = wa1.z; Ws[ac + 7][ah] = wa1.w;
    *(float4*)&Xs[bf][btq] = xv;
    __syncthreads();
#pragma unroll
    for (int f = 0; f < 16; ++f) {
      float4 a0 = *(const float4*)&Ws[f][ty * 8];
      float4 a1 = *(const float4*)&Ws[f][ty * 8 + 4];
      float4 xr = *(const float4*)&Xs[f][tx * 4];
      float av[8] = {a0.x, a0.y, a0.z, a0.w, a1.x, a1.y, a1.z, a1.w};
      float xw[4] = {xr.x, xr.y, xr.z, xr.w};
#pragma unroll
      for (int i = 0; i < 8; ++i)
#pragma unroll
        for (int j = 0; j < 4; ++j)
          acc[i][j] = fmaf(av[i], xw[j], acc[i][j]);
    }
  }
#pragma unroll
  for (int i = 0; i < 8; ++i) {
    float4 o{acc[i][0], acc[i][1], acc[i][2], acc[i][3]};
    *(float4*)&Zb[(size_t)(m0 + ty * 8 + i) * T + tt0 + tx * 4] = o;
  }
}

// ---------------- CUBA scan: in-place z->v, emit spikes, count ----------------
// volts emitted PRE-reset; carry voltage hard-reset to 0 when v >= 1.25.
__global__ __launch_bounds__(64) void scan_kernel(float* __restrict__ VZ,
                                                  float* __restrict__ S,
                                                  int* __restrict__ cnt) {
  const int g = blockIdx.x * 64 + threadIdx.x;  // (b,h) row, 0..32767
  const size_t base = (size_t)g * 256;
  const float CD = 0.75f;                 // 1 - CUR_DECAY (exact)
  const float VD = (float)(1.0 - 0.03);   // double-computed, cast to f32 (matches Python)
  float cur = 0.f, volt = 0.f;
  int c = 0;
#pragma unroll 1
  for (int tc = 0; tc < 16; ++tc) {
    float4 z0 = *(const float4*)&VZ[base + tc * 16 + 0];
    float4 z1 = *(const float4*)&VZ[base + tc * 16 + 4];
    float4 z2 = *(const float4*)&VZ[base + tc * 16 + 8];
    float4 z3 = *(const float4*)&VZ[base + tc * 16 + 12];
    float zv[16] = {z0.x, z0.y, z0.z, z0.w, z1.x, z1.y, z1.z, z1.w,
                    z2.x, z2.y, z2.z, z2.w, z3.x, z3.y, z3.z, z3.w};
    float vv[16], sv[16];
#pragma unroll
    for (int j = 0; j < 16; ++j) {
      cur = CD * cur + zv[j];
      volt = VD * volt + cur;
      vv[j] = volt;                 // pre-reset voltage is the output
      bool sp = volt >= 1.25f;
      sv[j] = sp ? 1.0f : 0.0f;
      c += sp ? 1 : 0;
      volt = sp ? 0.f : volt;       // hard reset for the carry
    }
    float4 o;
    o = {vv[0], vv[1], vv[2], vv[3]};     *(float4*)&VZ[base + tc * 16 + 0]  = o;
    o = {vv[4], vv[5], vv[6], vv[7]};     *(float4*)&VZ[base + tc * 16 + 4]  = o;
    o = {vv[8], vv[9], vv[10], vv[11]};   *(float4*)&VZ[base + tc * 16 + 8]  = o;
    o = {vv[12], vv[13], vv[14], vv[15]}; *(float4*)&VZ[base + tc * 16 + 12] = o;
    o = {sv[0], sv[1], sv[2], sv[3]};     *(float4*)&S[base + tc * 16 + 0]   = o;
    o = {sv[4], sv[5], sv[6], sv[7]};     *(float4*)&S[base + tc * 16 + 4]   = o;
    o = {sv[8], sv[9], sv[10], sv[11]};   *(float4*)&S[base + tc * 16 + 8]   = o;
    o = {sv[12], sv[13], sv[14], sv[15]}; *(float4*)&S[base + tc * 16 + 12]  = o;
  }
#pragma unroll
  for (int off = 32; off > 0; off >>= 1) c += __shfl_down(c, off);
  if (threadIdx.x == 0) atomicAdd(cnt, c);
}

// ---------------- readouts: O[b,o,t] = sum_h R[o,h] * S[b,h,t] ----------------
// M=128 fixed; split-K by 4 (256 each) + f32 atomicAdd into zeroed output.
// grid.z: 0..31 -> (R1,S1,O1) batch b ; 32..63 -> (R2,S2,O2).
__global__ __launch_bounds__(256) void readout_kernel(
    const float* __restrict__ R1, const float* __restrict__ R2,
    const float* __restrict__ S1, const float* __restrict__ S2,
    float* __restrict__ O1, float* __restrict__ O2) {
  const int T = 256, K = 1024;
  const int tt0  = blockIdx.x * 64;
  const int kbeg = blockIdx.y * 256;
  const int zz   = blockIdx.z;
  const int b    = zz & 31;
  const float* __restrict__ R  = (zz < 32) ? R1 : R2;
  const float* __restrict__ Sb = ((zz < 32) ? S1 : S2) + (size_t)b * K * T;
  float* __restrict__ Ob       = ((zz < 32) ? O1 : O2) + (size_t)b * 128 * T;

  __shared__ float Ws[16][132];
  __shared__ float Xs[16][68];

  const int tid = threadIdx.x;
  const int tx = tid & 15;
  const int ty = tid >> 4;

  const int ah  = tid >> 1;        // R row 0..127 (== all of M)
  const int ac  = (tid & 1) * 8;
  const int bf  = tid >> 4;
  const int btq = (tid & 15) * 4;

  float acc[8][4];
#pragma unroll
  for (int i = 0; i < 8; ++i)
#pragma unroll
    for (int j = 0; j < 4; ++j) acc[i][j] = 0.f;

  const float* wp = &R[(size_t)ah * K + ac];
  const float* xp = &Sb[(size_t)bf * T + tt0 + btq];

  for (int k0 = kbeg; k0 < kbeg + 256; k0 += 16) {
    float4 wa0 = *(const float4*)(wp + k0);
    float4 wa1 = *(const float4*)(wp + k0 + 4);
    float4 xv  = *(const float4*)(xp + (size_t)k0 * T);
    __syncthreads();
    Ws[ac + 0][ah] = wa0.x; Ws[ac + 1][ah] = wa0.y;
    Ws[ac + 2][ah] = wa0.z; Ws[ac + 3][ah] = wa0.w;
    Ws[ac + 4][ah] = wa1.x; Ws[ac + 5][ah] = wa1.y;
    Ws[ac + 6][ah] = wa1.z; Ws[ac + 7][ah] = wa1.w;
    *(float4*)&Xs[bf][btq] = xv;
    __syncthreads();
#pragma unroll
    for (int f = 0; f < 16; ++f) {
      float4 a0 = *(const float4*)&Ws[f][ty * 8];
      float4 a1 = *(const float4*)&Ws[f][ty * 8 + 4];
      float4 xr = *(const float4*)&Xs[f][tx * 4];
      float av[8] = {a0.x, a0.y, a0.z, a0.w, a1.x, a1.y, a1.z, a1.w};
      float xw[4] = {xr.x, xr.y, xr.z, xr.w};
#pragma unroll
      for (int i = 0; i < 8; ++i)
#pragma unroll
        for (int j = 0; j < 4; ++j)
          acc[i][j] = fmaf(av[i], xw[j], acc[i][j]);
    }
  }
#pragma unroll
  for (int i = 0; i < 8; ++i)
#pragma unroll
    for (int j = 0; j < 4; ++j)
      atomicAdd(&Ob[(size_t)(ty * 8 + i) * T + tt0 + tx * 4 + j], acc[i][j]);
}

// ---------------- counts ----------------
__global__ void finalize_kernel(const int* __restrict__ cnt, float* __restrict__ c) {
  if (threadIdx.x == 0) {
    c[0] = (float)cnt[0] * (1.0f / 8388608.0f);
    c[1] = (float)cnt[1] * (1.0f / 8388608.0f);
  }
}

extern "C" void kernel_launch(void* const* d_in, const int* in_sizes, int n_in,
                              void* d_out, int out_size, void* d_ws, size_t ws_size,
                              hipStream_t stream) {
  const float* spike = (const float*)d_in[0];
  const float* W1 = (const float*)d_in[1];
  const float* W2 = (const float*)d_in[2];
  const float* R1 = (const float*)d_in[3];
  const float* R2 = (const float*)d_in[4];

  float* out = (float*)d_out;
  float* s1 = out;
  float* s2 = out + S_SZ;
  float* r1 = out + 2 * S_SZ;
  float* r2 = out + 2 * S_SZ + R_SZ;
  float* v1 = out + 2 * S_SZ + 2 * R_SZ;       // holds z1 then v1 (in place)
  float* v2 = out + 2 * S_SZ + 2 * R_SZ + S_SZ;
  float* cc = out + 4 * S_SZ + 2 * R_SZ;       // c1, c2
  int* cnt = (int*)d_ws;

  zero_r_kernel<<<2048, 256, 0, stream>>>(r1, cnt);                       // zeros r1+r2 (contiguous) + counters
  gemm_f32<<<dim3(4, 8, 32), 256, 0, stream>>>(W1, spike, v1, 1024, 512); // z1
  scan_kernel<<<512, 64, 0, stream>>>(v1, s1, cnt + 0);                   // v1, s1, count1
  gemm_f32<<<dim3(4, 8, 32), 256, 0, stream>>>(W2, s1, v2, 1024, 1024);   // z2
  scan_kernel<<<512, 64, 0, stream>>>(v2, s2, cnt + 1);                   // v2, s2, count2
  readout_kernel<<<dim3(4, 4, 64), 256, 0, stream>>>(R1, R2, s1, s2, r1, r2);
  finalize_kernel<<<1, 1, 0, stream>>>(cnt, cc);
}

// Round 3
// 422.235 us; speedup vs baseline: 1.5155x; 1.5155x over previous
//
#include <hip/hip_runtime.h>
#include <hip/hip_bf16.h>

// DECOLLE SNN forward, MI355X. B=32, F_IN=512, H=1024, OUT=128, T=256.
// Fast path: 3-way bf16-split MFMA GEMMs (exact for binary activations),
// weights pre-split into ws, activations pre-transposed to bf16 [b][t][k].
// Fallback (ws too small): round-1 f32 kernels.
// d_out layout (floats): s1[8M] s2[8M] r1[1M] r2[1M] v1[8M] v2[8M] c1 c2

#define S_SZ 8388608
#define R_SZ 1048576

typedef __attribute__((ext_vector_type(8))) short v8s;
typedef __attribute__((ext_vector_type(4))) float v4f;
typedef __attribute__((ext_vector_type(8))) unsigned short u8us;

static __device__ __forceinline__ unsigned short f2bf(float x) {
  union { __hip_bfloat16 b; unsigned short u; } cv;
  cv.b = __float2bfloat16(x);
  return cv.u;
}
static __device__ __forceinline__ float bf2f(unsigned short u) {
  union { __hip_bfloat16 b; unsigned short u; } cv;
  cv.u = u;
  return __bfloat162float(cv.b);
}

// ================= fast path =================

__global__ void zero_cnt_kernel(int* __restrict__ cnt) { cnt[0] = 0; cnt[1] = 0; }

// split W (f32) -> 3 bf16 planes hi/mid/lo (w = hi+mid+lo to ~2^-27 rel)
__global__ __launch_bounds__(256) void split_kernel(const float* __restrict__ W,
                                                    unsigned short* __restrict__ out,
                                                    int N) {
  const int i = blockIdx.x * 256 + threadIdx.x;
  if (i >= N) return;
  const float w0 = W[i];
  const unsigned short h = f2bf(w0);
  const float hf = bf2f(h);
  const float rm = w0 - hf;          // exact (Sterbenz)
  const unsigned short m = f2bf(rm);
  const float mf = bf2f(m);
  const unsigned short l = f2bf(rm - mf);
  out[i] = h; out[N + i] = m; out[2 * N + i] = l;
}

// transpose+convert: in f32 [b][R][256] -> out bf16 [b][256][R]
__global__ __launch_bounds__(256) void tcvt_kernel(const float* __restrict__ in,
                                                   unsigned short* __restrict__ out,
                                                   int R) {
  __shared__ float Ls[64][68];
  const int r0 = blockIdx.x * 64, c0 = blockIdx.y * 64, b = blockIdx.z;
  const int tid = threadIdx.x;
  const float* ip = in + ((size_t)b * R + r0) * 256 + c0;
#pragma unroll
  for (int it = 0; it < 4; ++it) {
    const int row = it * 16 + (tid >> 4), col = (tid & 15) * 4;
    const float4 v = *(const float4*)&ip[(size_t)row * 256 + col];
    *(float4*)&Ls[row][col] = v;
  }
  __syncthreads();
  const int c = tid >> 2, rs = (tid & 3) * 16;
  unsigned short h[16];
#pragma unroll
  for (int j = 0; j < 16; ++j) h[j] = f2bf(Ls[rs + j][c]);
  u8us p0, p1;
#pragma unroll
  for (int j = 0; j < 8; ++j) { p0[j] = h[j]; p1[j] = h[8 + j]; }
  unsigned short* op = out + ((size_t)b * 256 + c0 + c) * R + r0 + rs;
  *(u8us*)(op) = p0;
  *(u8us*)(op + 8) = p1;
}

// Z[b][m][t] = sum_s sum_k Asp[s][m][k] * XT[b][t][k]   (bf16 MFMA, f32 acc)
// Block: 256 thr (4 waves, 2m x 2t), tile 128m x 64t, K-chunk 64, 2 b's/block.
// A staged via global_load_lds with XOR-swizzled source (G4/m173); B direct->reg.
__global__ __launch_bounds__(256) void gemm_mfma(
    const unsigned short* __restrict__ Asp,  // [3][M][K] bf16
    const unsigned short* __restrict__ XT,   // [32][256][K] bf16
    float* __restrict__ Z,                   // [32][M][256] f32
    int M, int K) {
  __shared__ unsigned short Alds[3 * 128 * 64];  // 48 KB
  const int t0 = blockIdx.x * 64;
  const int m0 = blockIdx.y * 128;
  const int bg = blockIdx.z;  // handles b = 2*bg, 2*bg+1
  const int tid = threadIdx.x;
  const int w = tid >> 6, lane = tid & 63;
  const int r = lane & 15, q = lane >> 4;
  const int wm = w >> 1, wt = w & 1;
  const int srow = lane >> 3, sslot = lane & 7;

  v4f acc[2][4][2];
#pragma unroll
  for (int ib = 0; ib < 2; ++ib)
#pragma unroll
    for (int f = 0; f < 4; ++f)
#pragma unroll
      for (int g = 0; g < 2; ++g) acc[ib][f][g] = (v4f){0.f, 0.f, 0.f, 0.f};

  const size_t MK = (size_t)M * K;
  const int nkc = K >> 6;

  for (int kc = 0; kc < nkc; ++kc) {
    const int k0 = kc << 6;
    // stage A: 3 planes x [128 rows][64 k] bf16, linear LDS, source XOR-swizzled
#pragma unroll
    for (int s = 0; s < 3; ++s)
#pragma unroll
      for (int c = 0; c < 4; ++c) {
        const int row = w * 32 + c * 8 + srow;
        const unsigned short* src = Asp + (size_t)s * MK + (size_t)(m0 + row) * K +
                                    k0 + ((sslot ^ (row & 7)) << 3);
        unsigned short* dst = &Alds[s * 8192 + (w * 32 + c * 8) * 64];
        __builtin_amdgcn_global_load_lds(
            (const __attribute__((address_space(1))) unsigned int*)src,
            (__attribute__((address_space(3))) unsigned int*)dst, 16, 0, 0);
      }
    // prefetch B fragments (rows of XT[t][k]; same lane->(idx,k) pattern as A)
    v8s bfr[2][2][2];
#pragma unroll
    for (int ib = 0; ib < 2; ++ib) {
      const size_t xbase = ((size_t)(bg * 2 + ib) * 256) * K;
#pragma unroll
      for (int ks = 0; ks < 2; ++ks)
#pragma unroll
        for (int g = 0; g < 2; ++g) {
          const int t = t0 + wt * 32 + g * 16 + r;
          bfr[ib][ks][g] =
              *(const v8s*)(XT + xbase + (size_t)t * K + k0 + ks * 32 + q * 8);
        }
    }
    __syncthreads();
#pragma unroll
    for (int ks = 0; ks < 2; ++ks)
#pragma unroll
      for (int s = 0; s < 3; ++s)
#pragma unroll
        for (int f = 0; f < 4; ++f) {
          const int arow = wm * 64 + f * 16 + r;
          const v8s a = *(const v8s*)&Alds[s * 8192 + arow * 64 +
                                           (((ks * 4 + q) ^ (arow & 7)) << 3)];
#pragma unroll
          for (int ib = 0; ib < 2; ++ib) {
            acc[ib][f][0] = __builtin_amdgcn_mfma_f32_16x16x32_bf16(
                a, bfr[ib][ks][0], acc[ib][f][0], 0, 0, 0);
            acc[ib][f][1] = __builtin_amdgcn_mfma_f32_16x16x32_bf16(
                a, bfr[ib][ks][1], acc[ib][f][1], 0, 0, 0);
          }
        }
    __syncthreads();
  }
  // epilogue: C/D map col=lane&15 (t), row=q*4+e (m)  [m89-verified]
#pragma unroll
  for (int ib = 0; ib < 2; ++ib) {
    float* Zb = Z + ((size_t)(bg * 2 + ib) * M) * 256;
#pragma unroll
    for (int f = 0; f < 4; ++f)
#pragma unroll
      for (int g = 0; g < 2; ++g)
#pragma unroll
        for (int e = 0; e < 4; ++e)
          Zb[(size_t)(m0 + wm * 64 + f * 16 + q * 4 + e) * 256 +
             t0 + wt * 32 + g * 16 + r] = acc[ib][f][g][e];
  }
}

// ================= CUBA scan (shared by both paths) =================
__global__ __launch_bounds__(64) void scan_kernel(float* __restrict__ VZ,
                                                  float* __restrict__ S,
                                                  int* __restrict__ cnt) {
  const int g = blockIdx.x * 64 + threadIdx.x;  // (b,h) row
  float* vz = VZ + (size_t)g * 256;
  float* sp = S + (size_t)g * 256;
  const float CD = 0.75f;
  const float VD = (float)(1.0 - 0.03);
  float cur = 0.f, volt = 0.f;
  int c = 0;
  float4 n0 = *(const float4*)(vz + 0), n1 = *(const float4*)(vz + 4);
  float4 n2 = *(const float4*)(vz + 8), n3 = *(const float4*)(vz + 12);
  for (int tc = 0; tc < 16; ++tc) {
    float zv[16] = {n0.x, n0.y, n0.z, n0.w, n1.x, n1.y, n1.z, n1.w,
                    n2.x, n2.y, n2.z, n2.w, n3.x, n3.y, n3.z, n3.w};
    if (tc < 15) {  // prefetch next chunk before the dependent compute
      const float* np = vz + (tc + 1) * 16;
      n0 = *(const float4*)(np + 0);  n1 = *(const float4*)(np + 4);
      n2 = *(const float4*)(np + 8);  n3 = *(const float4*)(np + 12);
    }
    float vv[16], sv[16];
#pragma unroll
    for (int j = 0; j < 16; ++j) {
      cur = CD * cur + zv[j];
      volt = VD * volt + cur;
      vv[j] = volt;  // pre-reset voltage
      const bool spk = volt >= 1.25f;
      sv[j] = spk ? 1.0f : 0.0f;
      c += spk ? 1 : 0;
      volt = spk ? 0.f : volt;
    }
    float4 o;
    o = {vv[0], vv[1], vv[2], vv[3]};     *(float4*)(vz + tc * 16 + 0) = o;
    o = {vv[4], vv[5], vv[6], vv[7]};     *(float4*)(vz + tc * 16 + 4) = o;
    o = {vv[8], vv[9], vv[10], vv[11]};   *(float4*)(vz + tc * 16 + 8) = o;
    o = {vv[12], vv[13], vv[14], vv[15]}; *(float4*)(vz + tc * 16 + 12) = o;
    o = {sv[0], sv[1], sv[2], sv[3]};     *(float4*)(sp + tc * 16 + 0) = o;
    o = {sv[4], sv[5], sv[6], sv[7]};     *(float4*)(sp + tc * 16 + 4) = o;
    o = {sv[8], sv[9], sv[10], sv[11]};   *(float4*)(sp + tc * 16 + 8) = o;
    o = {sv[12], sv[13], sv[14], sv[15]}; *(float4*)(sp + tc * 16 + 12) = o;
  }
#pragma unroll
  for (int off = 32; off > 0; off >>= 1) c += __shfl_down(c, off);
  if (threadIdx.x == 0) atomicAdd(cnt, c);
}

__global__ void finalize_kernel(const int* __restrict__ cnt, float* __restrict__ c) {
  if (threadIdx.x == 0) {
    c[0] = (float)cnt[0] * (1.0f / 8388608.0f);
    c[1] = (float)cnt[1] * (1.0f / 8388608.0f);
  }
}

// ================= fallback path (round-1 f32 kernels) =================

__global__ __launch_bounds__(256) void zero_r_kernel(float* __restrict__ r,
                                                     int* __restrict__ cnt) {
  int i = blockIdx.x * 256 + threadIdx.x;
  float4 z{0.f, 0.f, 0.f, 0.f};
  *(float4*)&r[(size_t)i * 4] = z;
  if (i == 0) { cnt[0] = 0; cnt[1] = 0; }
}

__global__ __launch_bounds__(256) void gemm_f32(
    const float* __restrict__ W, const float* __restrict__ X,
    float* __restrict__ Z, int M, int K) {
  const int T = 256;
  const int tt0 = blockIdx.x * 64;
  const int m0 = blockIdx.y * 128;
  const int b = blockIdx.z;
  const float* __restrict__ Xb = X + (size_t)b * K * T;
  float* __restrict__ Zb = Z + (size_t)b * M * T;
  __shared__ float Ws[16][132];
  __shared__ float Xs[16][68];
  const int tid = threadIdx.x;
  const int tx = tid & 15, ty = tid >> 4;
  const int ah = tid >> 1, ac = (tid & 1) * 8;
  const int bf = tid >> 4, btq = (tid & 15) * 4;
  float acc[8][4];
#pragma unroll
  for (int i = 0; i < 8; ++i)
#pragma unroll
    for (int j = 0; j < 4; ++j) acc[i][j] = 0.f;
  const float* wp = &W[(size_t)(m0 + ah) * K + ac];
  const float* xp = &Xb[(size_t)bf * T + tt0 + btq];
  for (int k0 = 0; k0 < K; k0 += 16) {
    float4 wa0 = *(const float4*)(wp + k0);
    float4 wa1 = *(const float4*)(wp + k0 + 4);
    float4 xv = *(const float4*)(xp + (size_t)k0 * T);
    __syncthreads();
    Ws[ac + 0][ah] = wa0.x; Ws[ac + 1][ah] = wa0.y;
    Ws[ac + 2][ah] = wa0.z; Ws[ac + 3][ah] = wa0.w;
    Ws[ac + 4][ah] = wa1.x; Ws[ac + 5][ah] = wa1.y;
    Ws[ac + 6][ah] = wa1.z; Ws[ac + 7][ah] = wa1.w;
    *(float4*)&Xs[bf][btq] = xv;
    __syncthreads();
#pragma unroll
    for (int f = 0; f < 16; ++f) {
      float4 a0 = *(const float4*)&Ws[f][ty * 8];
      float4 a1 = *(const float4*)&Ws[f][ty * 8 + 4];
      float4 xr = *(const float4*)&Xs[f][tx * 4];
      float av[8] = {a0.x, a0.y, a0.z, a0.w, a1.x, a1.y, a1.z, a1.w};
      float xw[4] = {xr.x, xr.y, xr.z, xr.w};
#pragma unroll
      for (int i = 0; i < 8; ++i)
#pragma unroll
        for (int j = 0; j < 4; ++j) acc[i][j] = fmaf(av[i], xw[j], acc[i][j]);
    }
  }
#pragma unroll
  for (int i = 0; i < 8; ++i) {
    float4 o{acc[i][0], acc[i][1], acc[i][2], acc[i][3]};
    *(float4*)&Zb[(size_t)(m0 + ty * 8 + i) * T + tt0 + tx * 4] = o;
  }
}

__global__ __launch_bounds__(256) void readout_kernel(
    const float* __restrict__ R1, const float* __restrict__ R2,
    const float* __restrict__ S1, const float* __restrict__ S2,
    float* __restrict__ O1, float* __restrict__ O2) {
  const int T = 256, K = 1024;
  const int tt0 = blockIdx.x * 64;
  const int kbeg = blockIdx.y * 256;
  const int zz = blockIdx.z;
  const int b = zz & 31;
  const float* __restrict__ R = (zz < 32) ? R1 : R2;
  const float* __restrict__ Sb = ((zz < 32) ? S1 : S2) + (size_t)b * K * T;
  float* __restrict__ Ob = ((zz < 32) ? O1 : O2) + (size_t)b * 128 * T;
  __shared__ float Ws[16][132];
  __shared__ float Xs[16][68];
  const int tid = threadIdx.x;
  const int tx = tid & 15, ty = tid >> 4;
  const int ah = tid >> 1, ac = (tid & 1) * 8;
  const int bf = tid >> 4, btq = (tid & 15) * 4;
  float acc[8][4];
#pragma unroll
  for (int i = 0; i < 8; ++i)
#pragma unroll
    for (int j = 0; j < 4; ++j) acc[i][j] = 0.f;
  const float* wp = &R[(size_t)ah * K + ac];
  const float* xp = &Sb[(size_t)bf * T + tt0 + btq];
  for (int k0 = kbeg; k0 < kbeg + 256; k0 += 16) {
    float4 wa0 = *(const float4*)(wp + k0);
    float4 wa1 = *(const float4*)(wp + k0 + 4);
    float4 xv = *(const float4*)(xp + (size_t)k0 * T);
    __syncthreads();
    Ws[ac + 0][ah] = wa0.x; Ws[ac + 1][ah] = wa0.y;
    Ws[ac + 2][ah] = wa0.z; Ws[ac + 3][ah] = wa0.w;
    Ws[ac + 4][ah] = wa1.x; Ws[ac + 5][ah] = wa1.y;
    Ws[ac + 6][ah] = wa1.z; Ws[ac + 7][ah] = wa1.w;
    *(float4*)&Xs[bf][btq] = xv;
    __syncthreads();
#pragma unroll
    for (int f = 0; f < 16; ++f) {
      float4 a0 = *(const float4*)&Ws[f][ty * 8];
      float4 a1 = *(const float4*)&Ws[f][ty * 8 + 4];
      float4 xr = *(const float4*)&Xs[f][tx * 4];
      float av[8] = {a0.x, a0.y, a0.z, a0.w, a1.x, a1.y, a1.z, a1.w};
      float xw[4] = {xr.x, xr.y, xr.z, xr.w};
#pragma unroll
      for (int i = 0; i < 8; ++i)
#pragma unroll
        for (int j = 0; j < 4; ++j) acc[i][j] = fmaf(av[i], xw[j], acc[i][j]);
    }
  }
#pragma unroll
  for (int i = 0; i < 8; ++i)
#pragma unroll
    for (int j = 0; j < 4; ++j)
      atomicAdd(&Ob[(size_t)(ty * 8 + i) * T + tt0 + tx * 4 + j], acc[i][j]);
}

// ================= launch =================
extern "C" void kernel_launch(void* const* d_in, const int* in_sizes, int n_in,
                              void* d_out, int out_size, void* d_ws, size_t ws_size,
                              hipStream_t stream) {
  const float* spike = (const float*)d_in[0];
  const float* W1 = (const float*)d_in[1];
  const float* W2 = (const float*)d_in[2];
  const float* R1 = (const float*)d_in[3];
  const float* R2 = (const float*)d_in[4];

  float* out = (float*)d_out;
  float* s1 = out;
  float* s2 = out + S_SZ;
  float* r1 = out + 2 * S_SZ;
  float* r2 = out + 2 * S_SZ + R_SZ;
  float* v1 = out + 2 * S_SZ + 2 * R_SZ;  // z1 then v1, in place
  float* v2 = out + 2 * S_SZ + 2 * R_SZ + S_SZ;
  float* cc = out + 4 * S_SZ + 2 * R_SZ;

  int* cnt = (int*)d_ws;
  unsigned short* w1s = (unsigned short*)((char*)d_ws + 64);
  unsigned short* w2s = w1s + 3 * 524288;
  unsigned short* r1s = w2s + 3 * 1048576;
  unsigned short* r2s = r1s + 3 * 131072;
  unsigned short* xT  = r2s + 3 * 131072;
  unsigned short* s1T = xT + 4194304;
  unsigned short* s2T = s1T + 8388608;
  const size_t WS_NEED = 53000000;  // 52,953,152 rounded up

  if (ws_size >= WS_NEED) {
    zero_cnt_kernel<<<1, 1, 0, stream>>>(cnt);
    split_kernel<<<2048, 256, 0, stream>>>(W1, w1s, 524288);
    split_kernel<<<4096, 256, 0, stream>>>(W2, w2s, 1048576);
    split_kernel<<<512, 256, 0, stream>>>(R1, r1s, 131072);
    split_kernel<<<512, 256, 0, stream>>>(R2, r2s, 131072);
    tcvt_kernel<<<dim3(8, 4, 32), 256, 0, stream>>>(spike, xT, 512);
    gemm_mfma<<<dim3(4, 8, 16), 256, 0, stream>>>(w1s, xT, v1, 1024, 512);
    scan_kernel<<<512, 64, 0, stream>>>(v1, s1, cnt + 0);
    tcvt_kernel<<<dim3(16, 4, 32), 256, 0, stream>>>(s1, s1T, 1024);
    gemm_mfma<<<dim3(4, 8, 16), 256, 0, stream>>>(w2s, s1T, v2, 1024, 1024);
    scan_kernel<<<512, 64, 0, stream>>>(v2, s2, cnt + 1);
    tcvt_kernel<<<dim3(16, 4, 32), 256, 0, stream>>>(s2, s2T, 1024);
    gemm_mfma<<<dim3(4, 1, 16), 256, 0, stream>>>(r1s, s1T, r1, 128, 1024);
    gemm_mfma<<<dim3(4, 1, 16), 256, 0, stream>>>(r2s, s2T, r2, 128, 1024);
    finalize_kernel<<<1, 1, 0, stream>>>(cnt, cc);
  } else {
    zero_r_kernel<<<2048, 256, 0, stream>>>(r1, cnt);
    gemm_f32<<<dim3(4, 8, 32), 256, 0, stream>>>(W1, spike, v1, 1024, 512);
    scan_kernel<<<512, 64, 0, stream>>>(v1, s1, cnt + 0);
    gemm_f32<<<dim3(4, 8, 32), 256, 0, stream>>>(W2, s1, v2, 1024, 1024);
    scan_kernel<<<512, 64, 0, stream>>>(v2, s2, cnt + 1);
    readout_kernel<<<dim3(4, 4, 64), 256, 0, stream>>>(R1, R2, s1, s2, r1, r2);
    finalize_kernel<<<1, 1, 0, stream>>>(cnt, cc);
  }
}

// Round 4
// 347.864 us; speedup vs baseline: 1.8394x; 1.2138x over previous
//
#include <hip/hip_runtime.h>
#include <hip/hip_bf16.h>

// DECOLLE SNN forward, MI355X. B=32, F_IN=512, H=1024, OUT=128, T=256.
// Fast path: 3-way bf16-split MFMA GEMMs (exact for binary activations).
// Round 4: scan fuses bf16 [b][t][h] spike-transpose write (kills 2 tcvt),
// 4-deep scan prefetch, fused readout kernel (256 blocks), merged splits.
// d_out layout (floats): s1[8M] s2[8M] r1[1M] r2[1M] v1[8M] v2[8M] c1 c2

#define S_SZ 8388608
#define R_SZ 1048576

typedef __attribute__((ext_vector_type(8))) short v8s;
typedef __attribute__((ext_vector_type(4))) float v4f;
typedef __attribute__((ext_vector_type(8))) unsigned short u8us;

static __device__ __forceinline__ unsigned short f2bf(float x) {
  union { __hip_bfloat16 b; unsigned short u; } cv;
  cv.b = __float2bfloat16(x);
  return cv.u;
}
static __device__ __forceinline__ float bf2f(unsigned short u) {
  union { __hip_bfloat16 b; unsigned short u; } cv;
  cv.u = u;
  return __bfloat162float(cv.b);
}

// ================= fast path =================

// one launch: split all 4 weight tensors into 3 bf16 planes + zero counters
__global__ __launch_bounds__(256) void split_all_kernel(
    const float* __restrict__ W1, const float* __restrict__ W2,
    const float* __restrict__ R1, const float* __restrict__ R2,
    unsigned short* __restrict__ w1s, unsigned short* __restrict__ w2s,
    unsigned short* __restrict__ r1s, unsigned short* __restrict__ r2s,
    int* __restrict__ cnt) {
  if (blockIdx.y == 0 && blockIdx.x == 0 && threadIdx.x == 0) {
    cnt[0] = 0; cnt[1] = 0;
  }
  const int i = blockIdx.x * 256 + threadIdx.x;
  const float* W; unsigned short* out; int N;
  switch (blockIdx.y) {
    case 0: W = W1; out = w1s; N = 524288; break;
    case 1: W = W2; out = w2s; N = 1048576; break;
    case 2: W = R1; out = r1s; N = 131072; break;
    default: W = R2; out = r2s; N = 131072; break;
  }
  if (i >= N) return;
  const float w0 = W[i];
  const unsigned short h = f2bf(w0);
  const float hf = bf2f(h);
  const float rm = w0 - hf;
  const unsigned short m = f2bf(rm);
  const float mf = bf2f(m);
  const unsigned short l = f2bf(rm - mf);
  out[i] = h; out[N + i] = m; out[2 * N + i] = l;
}

// transpose+convert input spikes: f32 [b][512][256] -> bf16 [b][256][512]
__global__ __launch_bounds__(256) void tcvt_kernel(const float* __restrict__ in,
                                                   unsigned short* __restrict__ out,
                                                   int R) {
  __shared__ float Ls[64][68];
  const int r0 = blockIdx.x * 64, c0 = blockIdx.y * 64, b = blockIdx.z;
  const int tid = threadIdx.x;
  const float* ip = in + ((size_t)b * R + r0) * 256 + c0;
#pragma unroll
  for (int it = 0; it < 4; ++it) {
    const int row = it * 16 + (tid >> 4), col = (tid & 15) * 4;
    const float4 v = *(const float4*)&ip[(size_t)row * 256 + col];
    *(float4*)&Ls[row][col] = v;
  }
  __syncthreads();
  const int c = tid >> 2, rs = (tid & 3) * 16;
  unsigned short h[16];
#pragma unroll
  for (int j = 0; j < 16; ++j) h[j] = f2bf(Ls[rs + j][c]);
  u8us p0, p1;
#pragma unroll
  for (int j = 0; j < 8; ++j) { p0[j] = h[j]; p1[j] = h[8 + j]; }
  unsigned short* op = out + ((size_t)b * 256 + c0 + c) * R + r0 + rs;
  *(u8us*)(op) = p0;
  *(u8us*)(op + 8) = p1;
}

// Z[b][m][t] = sum_s sum_k Asp[s][m][k] * XT[b][t][k]   (bf16 MFMA, f32 acc)
// 4 waves (2m x 2t), tile 128m x 64t, K-chunk 64, 2 batches/block.
__global__ __launch_bounds__(256) void gemm_mfma(
    const unsigned short* __restrict__ Asp,  // [3][M][K] bf16
    const unsigned short* __restrict__ XT,   // [32][256][K] bf16
    float* __restrict__ Z,                   // [32][M][256] f32
    int M, int K) {
  __shared__ unsigned short Alds[3 * 128 * 64];  // 48 KB
  const int t0 = blockIdx.x * 64;
  const int m0 = blockIdx.y * 128;
  const int bg = blockIdx.z;
  const int tid = threadIdx.x;
  const int w = tid >> 6, lane = tid & 63;
  const int r = lane & 15, q = lane >> 4;
  const int wm = w >> 1, wt = w & 1;
  const int srow = lane >> 3, sslot = lane & 7;

  v4f acc[2][4][2];
#pragma unroll
  for (int ib = 0; ib < 2; ++ib)
#pragma unroll
    for (int f = 0; f < 4; ++f)
#pragma unroll
      for (int g = 0; g < 2; ++g) acc[ib][f][g] = (v4f){0.f, 0.f, 0.f, 0.f};

  const size_t MK = (size_t)M * K;
  const int nkc = K >> 6;

  for (int kc = 0; kc < nkc; ++kc) {
    const int k0 = kc << 6;
#pragma unroll
    for (int s = 0; s < 3; ++s)
#pragma unroll
      for (int c = 0; c < 4; ++c) {
        const int row = w * 32 + c * 8 + srow;
        const unsigned short* src = Asp + (size_t)s * MK + (size_t)(m0 + row) * K +
                                    k0 + ((sslot ^ (row & 7)) << 3);
        unsigned short* dst = &Alds[s * 8192 + (w * 32 + c * 8) * 64];
        __builtin_amdgcn_global_load_lds(
            (const __attribute__((address_space(1))) unsigned int*)src,
            (__attribute__((address_space(3))) unsigned int*)dst, 16, 0, 0);
      }
    v8s bfr[2][2][2];
#pragma unroll
    for (int ib = 0; ib < 2; ++ib) {
      const size_t xbase = ((size_t)(bg * 2 + ib) * 256) * K;
#pragma unroll
      for (int ks = 0; ks < 2; ++ks)
#pragma unroll
        for (int g = 0; g < 2; ++g) {
          const int t = t0 + wt * 32 + g * 16 + r;
          bfr[ib][ks][g] =
              *(const v8s*)(XT + xbase + (size_t)t * K + k0 + ks * 32 + q * 8);
        }
    }
    __syncthreads();
#pragma unroll
    for (int ks = 0; ks < 2; ++ks)
#pragma unroll
      for (int s = 0; s < 3; ++s)
#pragma unroll
        for (int f = 0; f < 4; ++f) {
          const int arow = wm * 64 + f * 16 + r;
          const v8s a = *(const v8s*)&Alds[s * 8192 + arow * 64 +
                                           (((ks * 4 + q) ^ (arow & 7)) << 3)];
#pragma unroll
          for (int ib = 0; ib < 2; ++ib) {
            acc[ib][f][0] = __builtin_amdgcn_mfma_f32_16x16x32_bf16(
                a, bfr[ib][ks][0], acc[ib][f][0], 0, 0, 0);
            acc[ib][f][1] = __builtin_amdgcn_mfma_f32_16x16x32_bf16(
                a, bfr[ib][ks][1], acc[ib][f][1], 0, 0, 0);
          }
        }
    __syncthreads();
  }
#pragma unroll
  for (int ib = 0; ib < 2; ++ib) {
    float* Zb = Z + ((size_t)(bg * 2 + ib) * M) * 256;
#pragma unroll
    for (int f = 0; f < 4; ++f)
#pragma unroll
      for (int g = 0; g < 2; ++g)
#pragma unroll
        for (int e = 0; e < 4; ++e)
          Zb[(size_t)(m0 + wm * 64 + f * 16 + q * 4 + e) * 256 +
             t0 + wt * 32 + g * 16 + r] = acc[ib][f][g][e];
  }
}

// readouts: O[b][o][t] = sum_s sum_k Rsp[s][o][k] * ST[b][t][k]; M=128, K=1024
// grid (4 t-tiles, 2 nets, 32 b) = 256 blocks; count-finalize fused in.
__global__ __launch_bounds__(256) void readout_mfma(
    const unsigned short* __restrict__ r1s, const unsigned short* __restrict__ r2s,
    const unsigned short* __restrict__ s1T, const unsigned short* __restrict__ s2T,
    float* __restrict__ O1, float* __restrict__ O2,
    const int* __restrict__ cnt, float* __restrict__ cc) {
  if (blockIdx.x == 0 && blockIdx.y == 0 && blockIdx.z == 0 && threadIdx.x == 0) {
    cc[0] = (float)cnt[0] * (1.0f / 8388608.0f);
    cc[1] = (float)cnt[1] * (1.0f / 8388608.0f);
  }
  const int K = 1024;
  const int t0 = blockIdx.x * 64;
  const int net = blockIdx.y;
  const int b = blockIdx.z;
  const unsigned short* __restrict__ Asp = net ? r2s : r1s;
  const unsigned short* __restrict__ XT =
      (net ? s2T : s1T) + (size_t)b * 256 * K;
  float* __restrict__ Zb = (net ? O2 : O1) + (size_t)b * 128 * 256;

  __shared__ unsigned short Alds[3 * 128 * 64];  // 48 KB
  const int tid = threadIdx.x;
  const int w = tid >> 6, lane = tid & 63;
  const int r = lane & 15, q = lane >> 4;
  const int wm = w >> 1, wt = w & 1;
  const int srow = lane >> 3, sslot = lane & 7;

  v4f acc[4][2];
#pragma unroll
  for (int f = 0; f < 4; ++f)
#pragma unroll
    for (int g = 0; g < 2; ++g) acc[f][g] = (v4f){0.f, 0.f, 0.f, 0.f};

  const size_t MK = (size_t)128 * K;

  for (int kc = 0; kc < 16; ++kc) {
    const int k0 = kc << 6;
#pragma unroll
    for (int s = 0; s < 3; ++s)
#pragma unroll
      for (int c = 0; c < 4; ++c) {
        const int row = w * 32 + c * 8 + srow;
        const unsigned short* src = Asp + (size_t)s * MK + (size_t)row * K +
                                    k0 + ((sslot ^ (row & 7)) << 3);
        unsigned short* dst = &Alds[s * 8192 + (w * 32 + c * 8) * 64];
        __builtin_amdgcn_global_load_lds(
            (const __attribute__((address_space(1))) unsigned int*)src,
            (__attribute__((address_space(3))) unsigned int*)dst, 16, 0, 0);
      }
    v8s bfr[2][2];
#pragma unroll
    for (int ks = 0; ks < 2; ++ks)
#pragma unroll
      for (int g = 0; g < 2; ++g) {
        const int t = t0 + wt * 32 + g * 16 + r;
        bfr[ks][g] = *(const v8s*)(XT + (size_t)t * K + k0 + ks * 32 + q * 8);
      }
    __syncthreads();
#pragma unroll
    for (int ks = 0; ks < 2; ++ks)
#pragma unroll
      for (int s = 0; s < 3; ++s)
#pragma unroll
        for (int f = 0; f < 4; ++f) {
          const int arow = wm * 64 + f * 16 + r;
          const v8s a = *(const v8s*)&Alds[s * 8192 + arow * 64 +
                                           (((ks * 4 + q) ^ (arow & 7)) << 3)];
          acc[f][0] = __builtin_amdgcn_mfma_f32_16x16x32_bf16(
              a, bfr[ks][0], acc[f][0], 0, 0, 0);
          acc[f][1] = __builtin_amdgcn_mfma_f32_16x16x32_bf16(
              a, bfr[ks][1], acc[f][1], 0, 0, 0);
        }
    __syncthreads();
  }
#pragma unroll
  for (int f = 0; f < 4; ++f)
#pragma unroll
    for (int g = 0; g < 2; ++g)
#pragma unroll
      for (int e = 0; e < 4; ++e)
        Zb[(size_t)(wm * 64 + f * 16 + q * 4 + e) * 256 +
           t0 + wt * 32 + g * 16 + r] = acc[f][g][e];
}

// ================= CUBA scan =================
// in-place z->v, f32 spikes to S, bf16 transposed spikes to ST[b][t][h] (h=1024).
// 4-chunk-deep prefetch ring, fully unrolled (static indices only).
__global__ __launch_bounds__(64) void scan_kernel(float* __restrict__ VZ,
                                                  float* __restrict__ S,
                                                  unsigned short* __restrict__ ST,
                                                  int* __restrict__ cnt) {
  const int g = blockIdx.x * 64 + threadIdx.x;  // (b,h) row
  float* vz = VZ + (size_t)g * 256;
  float* sp = S + (size_t)g * 256;
  unsigned short* st =
      ST ? ST + ((size_t)(g >> 10) * 256) * 1024 + (g & 1023) : nullptr;
  const float CD = 0.75f;
  const float VD = (float)(1.0 - 0.03);

  float4 buf[4][4];
#pragma unroll
  for (int i = 0; i < 4; ++i)
#pragma unroll
    for (int qq = 0; qq < 4; ++qq)
      buf[i][qq] = *(const float4*)(vz + i * 16 + qq * 4);

  float cur = 0.f, volt = 0.f;
  int c = 0;
#pragma unroll
  for (int tc = 0; tc < 16; ++tc) {
    float zv[16];
    *(float4*)&zv[0]  = buf[tc & 3][0];
    *(float4*)&zv[4]  = buf[tc & 3][1];
    *(float4*)&zv[8]  = buf[tc & 3][2];
    *(float4*)&zv[12] = buf[tc & 3][3];
    if (tc < 12) {
#pragma unroll
      for (int qq = 0; qq < 4; ++qq)
        buf[tc & 3][qq] = *(const float4*)(vz + (tc + 4) * 16 + qq * 4);
    }
    float vv[16], sv[16];
    unsigned short sb[16];
#pragma unroll
    for (int j = 0; j < 16; ++j) {
      cur = CD * cur + zv[j];
      volt = VD * volt + cur;
      vv[j] = volt;  // pre-reset voltage
      const bool spk = volt >= 1.25f;
      sv[j] = spk ? 1.0f : 0.0f;
      sb[j] = spk ? 0x3F80 : 0;  // bf16(1.0) / bf16(0.0)
      c += spk ? 1 : 0;
      volt = spk ? 0.f : volt;
    }
    float4 o;
    o = {vv[0], vv[1], vv[2], vv[3]};     *(float4*)(vz + tc * 16 + 0) = o;
    o = {vv[4], vv[5], vv[6], vv[7]};     *(float4*)(vz + tc * 16 + 4) = o;
    o = {vv[8], vv[9], vv[10], vv[11]};   *(float4*)(vz + tc * 16 + 8) = o;
    o = {vv[12], vv[13], vv[14], vv[15]}; *(float4*)(vz + tc * 16 + 12) = o;
    o = {sv[0], sv[1], sv[2], sv[3]};     *(float4*)(sp + tc * 16 + 0) = o;
    o = {sv[4], sv[5], sv[6], sv[7]};     *(float4*)(sp + tc * 16 + 4) = o;
    o = {sv[8], sv[9], sv[10], sv[11]};   *(float4*)(sp + tc * 16 + 8) = o;
    o = {sv[12], sv[13], sv[14], sv[15]}; *(float4*)(sp + tc * 16 + 12) = o;
    if (st) {
#pragma unroll
      for (int j = 0; j < 16; ++j)
        st[(size_t)(tc * 16 + j) * 1024] = sb[j];
    }
  }
#pragma unroll
  for (int off = 32; off > 0; off >>= 1) c += __shfl_down(c, off);
  if (threadIdx.x == 0) atomicAdd(cnt, c);
}

__global__ void finalize_kernel(const int* __restrict__ cnt, float* __restrict__ c) {
  if (threadIdx.x == 0) {
    c[0] = (float)cnt[0] * (1.0f / 8388608.0f);
    c[1] = (float)cnt[1] * (1.0f / 8388608.0f);
  }
}

// ================= fallback path (round-1 f32 kernels) =================

__global__ __launch_bounds__(256) void zero_r_kernel(float* __restrict__ r,
                                                     int* __restrict__ cnt) {
  int i = blockIdx.x * 256 + threadIdx.x;
  float4 z{0.f, 0.f, 0.f, 0.f};
  *(float4*)&r[(size_t)i * 4] = z;
  if (i == 0) { cnt[0] = 0; cnt[1] = 0; }
}

__global__ __launch_bounds__(256) void gemm_f32(
    const float* __restrict__ W, const float* __restrict__ X,
    float* __restrict__ Z, int M, int K) {
  const int T = 256;
  const int tt0 = blockIdx.x * 64;
  const int m0 = blockIdx.y * 128;
  const int b = blockIdx.z;
  const float* __restrict__ Xb = X + (size_t)b * K * T;
  float* __restrict__ Zb = Z + (size_t)b * M * T;
  __shared__ float Ws[16][132];
  __shared__ float Xs[16][68];
  const int tid = threadIdx.x;
  const int tx = tid & 15, ty = tid >> 4;
  const int ah = tid >> 1, ac = (tid & 1) * 8;
  const int bf = tid >> 4, btq = (tid & 15) * 4;
  float acc[8][4];
#pragma unroll
  for (int i = 0; i < 8; ++i)
#pragma unroll
    for (int j = 0; j < 4; ++j) acc[i][j] = 0.f;
  const float* wp = &W[(size_t)(m0 + ah) * K + ac];
  const float* xp = &Xb[(size_t)bf * T + tt0 + btq];
  for (int k0 = 0; k0 < K; k0 += 16) {
    float4 wa0 = *(const float4*)(wp + k0);
    float4 wa1 = *(const float4*)(wp + k0 + 4);
    float4 xv = *(const float4*)(xp + (size_t)k0 * T);
    __syncthreads();
    Ws[ac + 0][ah] = wa0.x; Ws[ac + 1][ah] = wa0.y;
    Ws[ac + 2][ah] = wa0.z; Ws[ac + 3][ah] = wa0.w;
    Ws[ac + 4][ah] = wa1.x; Ws[ac + 5][ah] = wa1.y;
    Ws[ac + 6][ah] = wa1.z; Ws[ac + 7][ah] = wa1.w;
    *(float4*)&Xs[bf][btq] = xv;
    __syncthreads();
#pragma unroll
    for (int f = 0; f < 16; ++f) {
      float4 a0 = *(const float4*)&Ws[f][ty * 8];
      float4 a1 = *(const float4*)&Ws[f][ty * 8 + 4];
      float4 xr = *(const float4*)&Xs[f][tx * 4];
      float av[8] = {a0.x, a0.y, a0.z, a0.w, a1.x, a1.y, a1.z, a1.w};
      float xw[4] = {xr.x, xr.y, xr.z, xr.w};
#pragma unroll
      for (int i = 0; i < 8; ++i)
#pragma unroll
        for (int j = 0; j < 4; ++j) acc[i][j] = fmaf(av[i], xw[j], acc[i][j]);
    }
  }
#pragma unroll
  for (int i = 0; i < 8; ++i) {
    float4 o{acc[i][0], acc[i][1], acc[i][2], acc[i][3]};
    *(float4*)&Zb[(size_t)(m0 + ty * 8 + i) * T + tt0 + tx * 4] = o;
  }
}

__global__ __launch_bounds__(256) void readout_kernel(
    const float* __restrict__ R1, const float* __restrict__ R2,
    const float* __restrict__ S1, const float* __restrict__ S2,
    float* __restrict__ O1, float* __restrict__ O2) {
  const int T = 256, K = 1024;
  const int tt0 = blockIdx.x * 64;
  const int kbeg = blockIdx.y * 256;
  const int zz = blockIdx.z;
  const int b = zz & 31;
  const float* __restrict__ R = (zz < 32) ? R1 : R2;
  const float* __restrict__ Sb = ((zz < 32) ? S1 : S2) + (size_t)b * K * T;
  float* __restrict__ Ob = ((zz < 32) ? O1 : O2) + (size_t)b * 128 * T;
  __shared__ float Ws[16][132];
  __shared__ float Xs[16][68];
  const int tid = threadIdx.x;
  const int tx = tid & 15, ty = tid >> 4;
  const int ah = tid >> 1, ac = (tid & 1) * 8;
  const int bf = tid >> 4, btq = (tid & 15) * 4;
  float acc[8][4];
#pragma unroll
  for (int i = 0; i < 8; ++i)
#pragma unroll
    for (int j = 0; j < 4; ++j) acc[i][j] = 0.f;
  const float* wp = &R[(size_t)ah * K + ac];
  const float* xp = &Sb[(size_t)bf * T + tt0 + btq];
  for (int k0 = kbeg; k0 < kbeg + 256; k0 += 16) {
    float4 wa0 = *(const float4*)(wp + k0);
    float4 wa1 = *(const float4*)(wp + k0 + 4);
    float4 xv = *(const float4*)(xp + (size_t)k0 * T);
    __syncthreads();
    Ws[ac + 0][ah] = wa0.x; Ws[ac + 1][ah] = wa0.y;
    Ws[ac + 2][ah] = wa0.z; Ws[ac + 3][ah] = wa0.w;
    Ws[ac + 4][ah] = wa1.x; Ws[ac + 5][ah] = wa1.y;
    Ws[ac + 6][ah] = wa1.z; Ws[ac + 7][ah] = wa1.w;
    *(float4*)&Xs[bf][btq] = xv;
    __syncthreads();
#pragma unroll
    for (int f = 0; f < 16; ++f) {
      float4 a0 = *(const float4*)&Ws[f][ty * 8];
      float4 a1 = *(const float4*)&Ws[f][ty * 8 + 4];
      float4 xr = *(const float4*)&Xs[f][tx * 4];
      float av[8] = {a0.x, a0.y, a0.z, a0.w, a1.x, a1.y, a1.z, a1.w};
      float xw[4] = {xr.x, xr.y, xr.z, xr.w};
#pragma unroll
      for (int i = 0; i < 8; ++i)
#pragma unroll
        for (int j = 0; j < 4; ++j) acc[i][j] = fmaf(av[i], xw[j], acc[i][j]);
    }
  }
#pragma unroll
  for (int i = 0; i < 8; ++i)
#pragma unroll
    for (int j = 0; j < 4; ++j)
      atomicAdd(&Ob[(size_t)(ty * 8 + i) * T + tt0 + tx * 4 + j], acc[i][j]);
}

// ================= launch =================
extern "C" void kernel_launch(void* const* d_in, const int* in_sizes, int n_in,
                              void* d_out, int out_size, void* d_ws, size_t ws_size,
                              hipStream_t stream) {
  const float* spike = (const float*)d_in[0];
  const float* W1 = (const float*)d_in[1];
  const float* W2 = (const float*)d_in[2];
  const float* R1 = (const float*)d_in[3];
  const float* R2 = (const float*)d_in[4];

  float* out = (float*)d_out;
  float* s1 = out;
  float* s2 = out + S_SZ;
  float* r1 = out + 2 * S_SZ;
  float* r2 = out + 2 * S_SZ + R_SZ;
  float* v1 = out + 2 * S_SZ + 2 * R_SZ;  // z1 then v1, in place
  float* v2 = out + 2 * S_SZ + 2 * R_SZ + S_SZ;
  float* cc = out + 4 * S_SZ + 2 * R_SZ;

  int* cnt = (int*)d_ws;
  unsigned short* w1s = (unsigned short*)((char*)d_ws + 64);
  unsigned short* w2s = w1s + 3 * 524288;
  unsigned short* r1s = w2s + 3 * 1048576;
  unsigned short* r2s = r1s + 3 * 131072;
  unsigned short* xT  = r2s + 3 * 131072;
  unsigned short* s1T = xT + 4194304;
  unsigned short* s2T = s1T + 8388608;
  const size_t WS_NEED = 53000000;

  if (ws_size >= WS_NEED) {
    split_all_kernel<<<dim3(4096, 4), 256, 0, stream>>>(W1, W2, R1, R2, w1s, w2s,
                                                        r1s, r2s, cnt);
    tcvt_kernel<<<dim3(8, 4, 32), 256, 0, stream>>>(spike, xT, 512);
    gemm_mfma<<<dim3(4, 8, 16), 256, 0, stream>>>(w1s, xT, v1, 1024, 512);
    scan_kernel<<<512, 64, 0, stream>>>(v1, s1, s1T, cnt + 0);
    gemm_mfma<<<dim3(4, 8, 16), 256, 0, stream>>>(w2s, s1T, v2, 1024, 1024);
    scan_kernel<<<512, 64, 0, stream>>>(v2, s2, s2T, cnt + 1);
    readout_mfma<<<dim3(4, 2, 32), 256, 0, stream>>>(r1s, r2s, s1T, s2T, r1, r2,
                                                     cnt, cc);
  } else {
    zero_r_kernel<<<2048, 256, 0, stream>>>(r1, cnt);
    gemm_f32<<<dim3(4, 8, 32), 256, 0, stream>>>(W1, spike, v1, 1024, 512);
    scan_kernel<<<512, 64, 0, stream>>>(v1, s1, nullptr, cnt + 0);
    gemm_f32<<<dim3(4, 8, 32), 256, 0, stream>>>(W2, s1, v2, 1024, 1024);
    scan_kernel<<<512, 64, 0, stream>>>(v2, s2, nullptr, cnt + 1);
    readout_kernel<<<dim3(4, 4, 64), 256, 0, stream>>>(R1, R2, s1, s2, r1, r2);
    finalize_kernel<<<1, 1, 0, stream>>>(cnt, cc);
  }
}

// Round 5
// 346.113 us; speedup vs baseline: 1.8487x; 1.0051x over previous
//
#include <hip/hip_runtime.h>
#include <hip/hip_bf16.h>

// DECOLLE SNN forward, MI355X. B=32, F_IN=512, H=1024, OUT=128, T=256.
// Fast path: 3-way bf16-split MFMA GEMMs (exact for binary activations).
// Round 5: double-buffered single-plane LDS chunks (T3 minimum 2-phase
// pipeline) in gemm_mfma + readout_mfma; one sync per phase, stage-before-
// compute so global_load_lds latency hides under the MFMA phase.
// d_out layout (floats): s1[8M] s2[8M] r1[1M] r2[1M] v1[8M] v2[8M] c1 c2

#define S_SZ 8388608
#define R_SZ 1048576

typedef __attribute__((ext_vector_type(8))) short v8s;
typedef __attribute__((ext_vector_type(4))) float v4f;
typedef __attribute__((ext_vector_type(8))) unsigned short u8us;

static __device__ __forceinline__ unsigned short f2bf(float x) {
  union { __hip_bfloat16 b; unsigned short u; } cv;
  cv.b = __float2bfloat16(x);
  return cv.u;
}
static __device__ __forceinline__ float bf2f(unsigned short u) {
  union { __hip_bfloat16 b; unsigned short u; } cv;
  cv.u = u;
  return __bfloat162float(cv.b);
}

// ================= fast path =================

// one launch: split all 4 weight tensors into 3 bf16 planes + zero counters
__global__ __launch_bounds__(256) void split_all_kernel(
    const float* __restrict__ W1, const float* __restrict__ W2,
    const float* __restrict__ R1, const float* __restrict__ R2,
    unsigned short* __restrict__ w1s, unsigned short* __restrict__ w2s,
    unsigned short* __restrict__ r1s, unsigned short* __restrict__ r2s,
    int* __restrict__ cnt) {
  if (blockIdx.y == 0 && blockIdx.x == 0 && threadIdx.x == 0) {
    cnt[0] = 0; cnt[1] = 0;
  }
  const int i = blockIdx.x * 256 + threadIdx.x;
  const float* W; unsigned short* out; int N;
  switch (blockIdx.y) {
    case 0: W = W1; out = w1s; N = 524288; break;
    case 1: W = W2; out = w2s; N = 1048576; break;
    case 2: W = R1; out = r1s; N = 131072; break;
    default: W = R2; out = r2s; N = 131072; break;
  }
  if (i >= N) return;
  const float w0 = W[i];
  const unsigned short h = f2bf(w0);
  const float hf = bf2f(h);
  const float rm = w0 - hf;
  const unsigned short m = f2bf(rm);
  const float mf = bf2f(m);
  const unsigned short l = f2bf(rm - mf);
  out[i] = h; out[N + i] = m; out[2 * N + i] = l;
}

// transpose+convert input spikes: f32 [b][512][256] -> bf16 [b][256][512]
__global__ __launch_bounds__(256) void tcvt_kernel(const float* __restrict__ in,
                                                   unsigned short* __restrict__ out,
                                                   int R) {
  __shared__ float Ls[64][68];
  const int r0 = blockIdx.x * 64, c0 = blockIdx.y * 64, b = blockIdx.z;
  const int tid = threadIdx.x;
  const float* ip = in + ((size_t)b * R + r0) * 256 + c0;
#pragma unroll
  for (int it = 0; it < 4; ++it) {
    const int row = it * 16 + (tid >> 4), col = (tid & 15) * 4;
    const float4 v = *(const float4*)&ip[(size_t)row * 256 + col];
    *(float4*)&Ls[row][col] = v;
  }
  __syncthreads();
  const int c = tid >> 2, rs = (tid & 3) * 16;
  unsigned short h[16];
#pragma unroll
  for (int j = 0; j < 16; ++j) h[j] = f2bf(Ls[rs + j][c]);
  u8us p0, p1;
#pragma unroll
  for (int j = 0; j < 8; ++j) { p0[j] = h[j]; p1[j] = h[8 + j]; }
  unsigned short* op = out + ((size_t)b * 256 + c0 + c) * R + r0 + rs;
  *(u8us*)(op) = p0;
  *(u8us*)(op + 8) = p1;
}

// Z[b][m][t] = sum_s sum_k Asp[s][m][k] * XT[b][t][k]   (bf16 MFMA, f32 acc)
// 4 waves (2m x 2t), tile 128m x 64t, 2 batches/block.
// Pipeline: single-plane 16KB LDS chunks, double-buffered; STAGE(next) +
// BLOAD(next kc) issued before COMPUTE(cur); one __syncthreads per phase.
__global__ __launch_bounds__(256) void gemm_mfma(
    const unsigned short* __restrict__ Asp,  // [3][M][K] bf16
    const unsigned short* __restrict__ XT,   // [32][256][K] bf16
    float* __restrict__ Z,                   // [32][M][256] f32
    int M, int K) {
  __shared__ unsigned short Alds[2][128 * 64];  // 2 x 16 KB
  const int t0 = blockIdx.x * 64;
  const int m0 = blockIdx.y * 128;
  const int bg = blockIdx.z;
  const int tid = threadIdx.x;
  const int w = tid >> 6, lane = tid & 63;
  const int r = lane & 15, q = lane >> 4;
  const int wm = w >> 1, wt = w & 1;
  const int srow = lane >> 3, sslot = lane & 7;
  const size_t MK = (size_t)M * K;
  const int nkc = K >> 6;

  v4f acc[2][4][2];
#pragma unroll
  for (int ib = 0; ib < 2; ++ib)
#pragma unroll
    for (int f = 0; f < 4; ++f)
#pragma unroll
      for (int g = 0; g < 2; ++g) acc[ib][f][g] = (v4f){0.f, 0.f, 0.f, 0.f};

  auto STAGE = [&](int buf, int s, int kc) {
    const int k0 = kc << 6;
#pragma unroll
    for (int c = 0; c < 4; ++c) {
      const int row = w * 32 + c * 8 + srow;
      const unsigned short* src = Asp + (size_t)s * MK + (size_t)(m0 + row) * K +
                                  k0 + ((sslot ^ (row & 7)) << 3);
      unsigned short* dst = &Alds[buf][(w * 32 + c * 8) * 64];
      __builtin_amdgcn_global_load_lds(
          (const __attribute__((address_space(1))) unsigned int*)src,
          (__attribute__((address_space(3))) unsigned int*)dst, 16, 0, 0);
    }
  };
  auto BLOAD = [&](v8s (&bfr)[2][2][2], int kc) {
    const int k0 = kc << 6;
#pragma unroll
    for (int ib = 0; ib < 2; ++ib) {
      const size_t xbase = ((size_t)(bg * 2 + ib) * 256) * K;
#pragma unroll
      for (int ks = 0; ks < 2; ++ks)
#pragma unroll
        for (int g = 0; g < 2; ++g) {
          const int t = t0 + wt * 32 + g * 16 + r;
          bfr[ib][ks][g] =
              *(const v8s*)(XT + xbase + (size_t)t * K + k0 + ks * 32 + q * 8);
        }
    }
  };
  auto COMPUTE = [&](int buf, v8s (&bfr)[2][2][2]) {
#pragma unroll
    for (int ks = 0; ks < 2; ++ks)
#pragma unroll
      for (int f = 0; f < 4; ++f) {
        const int arow = wm * 64 + f * 16 + r;
        const v8s a = *(const v8s*)&Alds[buf][arow * 64 +
                                           (((ks * 4 + q) ^ (arow & 7)) << 3)];
#pragma unroll
        for (int ib = 0; ib < 2; ++ib) {
          acc[ib][f][0] = __builtin_amdgcn_mfma_f32_16x16x32_bf16(
              a, bfr[ib][ks][0], acc[ib][f][0], 0, 0, 0);
          acc[ib][f][1] = __builtin_amdgcn_mfma_f32_16x16x32_bf16(
              a, bfr[ib][ks][1], acc[ib][f][1], 0, 0, 0);
        }
      }
  };

  v8s bA[2][2][2], bB[2][2][2];
  STAGE(0, 0, 0);
  BLOAD(bA, 0);
  __syncthreads();
  int buf = 0;
  for (int kc = 0; kc < nkc; kc += 2) {
    STAGE(buf ^ 1, 1, kc);     COMPUTE(buf, bA); __syncthreads(); buf ^= 1;
    STAGE(buf ^ 1, 2, kc);     COMPUTE(buf, bA); __syncthreads(); buf ^= 1;
    STAGE(buf ^ 1, 0, kc + 1); BLOAD(bB, kc + 1);
                               COMPUTE(buf, bA); __syncthreads(); buf ^= 1;
    STAGE(buf ^ 1, 1, kc + 1); COMPUTE(buf, bB); __syncthreads(); buf ^= 1;
    STAGE(buf ^ 1, 2, kc + 1); COMPUTE(buf, bB); __syncthreads(); buf ^= 1;
    if (kc + 2 < nkc) { STAGE(buf ^ 1, 0, kc + 2); BLOAD(bA, kc + 2); }
                               COMPUTE(buf, bB); __syncthreads(); buf ^= 1;
  }

  // epilogue: C/D map col=lane&15 (t), row=q*4+e (m)  [m89-verified]
#pragma unroll
  for (int ib = 0; ib < 2; ++ib) {
    float* Zb = Z + ((size_t)(bg * 2 + ib) * M) * 256;
#pragma unroll
    for (int f = 0; f < 4; ++f)
#pragma unroll
      for (int g = 0; g < 2; ++g)
#pragma unroll
        for (int e = 0; e < 4; ++e)
          Zb[(size_t)(m0 + wm * 64 + f * 16 + q * 4 + e) * 256 +
             t0 + wt * 32 + g * 16 + r] = acc[ib][f][g][e];
  }
}

// readouts: O[b][o][t] = sum_s sum_k Rsp[s][o][k] * ST[b][t][k]; M=128, K=1024
// grid (4 t-tiles, 2 nets, 32 b) = 256 blocks; count-finalize fused in.
// Same double-buffered pipeline as gemm_mfma, single batch.
__global__ __launch_bounds__(256) void readout_mfma(
    const unsigned short* __restrict__ r1s, const unsigned short* __restrict__ r2s,
    const unsigned short* __restrict__ s1T, const unsigned short* __restrict__ s2T,
    float* __restrict__ O1, float* __restrict__ O2,
    const int* __restrict__ cnt, float* __restrict__ cc) {
  if (blockIdx.x == 0 && blockIdx.y == 0 && blockIdx.z == 0 && threadIdx.x == 0) {
    cc[0] = (float)cnt[0] * (1.0f / 8388608.0f);
    cc[1] = (float)cnt[1] * (1.0f / 8388608.0f);
  }
  const int K = 1024;
  const int t0 = blockIdx.x * 64;
  const int net = blockIdx.y;
  const int b = blockIdx.z;
  const unsigned short* __restrict__ Asp = net ? r2s : r1s;
  const unsigned short* __restrict__ XT = (net ? s2T : s1T) + (size_t)b * 256 * K;
  float* __restrict__ Zb = (net ? O2 : O1) + (size_t)b * 128 * 256;

  __shared__ unsigned short Alds[2][128 * 64];  // 2 x 16 KB
  const int tid = threadIdx.x;
  const int w = tid >> 6, lane = tid & 63;
  const int r = lane & 15, q = lane >> 4;
  const int wm = w >> 1, wt = w & 1;
  const int srow = lane >> 3, sslot = lane & 7;
  const size_t MK = (size_t)128 * K;
  const int nkc = 16;

  v4f acc[4][2];
#pragma unroll
  for (int f = 0; f < 4; ++f)
#pragma unroll
    for (int g = 0; g < 2; ++g) acc[f][g] = (v4f){0.f, 0.f, 0.f, 0.f};

  auto STAGE = [&](int buf, int s, int kc) {
    const int k0 = kc << 6;
#pragma unroll
    for (int c = 0; c < 4; ++c) {
      const int row = w * 32 + c * 8 + srow;
      const unsigned short* src = Asp + (size_t)s * MK + (size_t)row * K +
                                  k0 + ((sslot ^ (row & 7)) << 3);
      unsigned short* dst = &Alds[buf][(w * 32 + c * 8) * 64];
      __builtin_amdgcn_global_load_lds(
          (const __attribute__((address_space(1))) unsigned int*)src,
          (__attribute__((address_space(3))) unsigned int*)dst, 16, 0, 0);
    }
  };
  auto BLOAD = [&](v8s (&bfr)[2][2], int kc) {
    const int k0 = kc << 6;
#pragma unroll
    for (int ks = 0; ks < 2; ++ks)
#pragma unroll
      for (int g = 0; g < 2; ++g) {
        const int t = t0 + wt * 32 + g * 16 + r;
        bfr[ks][g] = *(const v8s*)(XT + (size_t)t * K + k0 + ks * 32 + q * 8);
      }
  };
  auto COMPUTE = [&](int buf, v8s (&bfr)[2][2]) {
#pragma unroll
    for (int ks = 0; ks < 2; ++ks)
#pragma unroll
      for (int f = 0; f < 4; ++f) {
        const int arow = wm * 64 + f * 16 + r;
        const v8s a = *(const v8s*)&Alds[buf][arow * 64 +
                                           (((ks * 4 + q) ^ (arow & 7)) << 3)];
        acc[f][0] = __builtin_amdgcn_mfma_f32_16x16x32_bf16(
            a, bfr[ks][0], acc[f][0], 0, 0, 0);
        acc[f][1] = __builtin_amdgcn_mfma_f32_16x16x32_bf16(
            a, bfr[ks][1], acc[f][1], 0, 0, 0);
      }
  };

  v8s bA[2][2], bB[2][2];
  STAGE(0, 0, 0);
  BLOAD(bA, 0);
  __syncthreads();
  int buf = 0;
  for (int kc = 0; kc < nkc; kc += 2) {
    STAGE(buf ^ 1, 1, kc);     COMPUTE(buf, bA); __syncthreads(); buf ^= 1;
    STAGE(buf ^ 1, 2, kc);     COMPUTE(buf, bA); __syncthreads(); buf ^= 1;
    STAGE(buf ^ 1, 0, kc + 1); BLOAD(bB, kc + 1);
                               COMPUTE(buf, bA); __syncthreads(); buf ^= 1;
    STAGE(buf ^ 1, 1, kc + 1); COMPUTE(buf, bB); __syncthreads(); buf ^= 1;
    STAGE(buf ^ 1, 2, kc + 1); COMPUTE(buf, bB); __syncthreads(); buf ^= 1;
    if (kc + 2 < nkc) { STAGE(buf ^ 1, 0, kc + 2); BLOAD(bA, kc + 2); }
                               COMPUTE(buf, bB); __syncthreads(); buf ^= 1;
  }

#pragma unroll
  for (int f = 0; f < 4; ++f)
#pragma unroll
    for (int g = 0; g < 2; ++g)
#pragma unroll
      for (int e = 0; e < 4; ++e)
        Zb[(size_t)(wm * 64 + f * 16 + q * 4 + e) * 256 +
           t0 + wt * 32 + g * 16 + r] = acc[f][g][e];
}

// ================= CUBA scan =================
// in-place z->v, f32 spikes to S, bf16 transposed spikes to ST[b][t][h] (h=1024).
// 4-chunk-deep prefetch ring, fully unrolled (static indices only).
__global__ __launch_bounds__(64) void scan_kernel(float* __restrict__ VZ,
                                                  float* __restrict__ S,
                                                  unsigned short* __restrict__ ST,
                                                  int* __restrict__ cnt) {
  const int g = blockIdx.x * 64 + threadIdx.x;  // (b,h) row
  float* vz = VZ + (size_t)g * 256;
  float* sp = S + (size_t)g * 256;
  unsigned short* st =
      ST ? ST + ((size_t)(g >> 10) * 256) * 1024 + (g & 1023) : nullptr;
  const float CD = 0.75f;
  const float VD = (float)(1.0 - 0.03);

  float4 buf[4][4];
#pragma unroll
  for (int i = 0; i < 4; ++i)
#pragma unroll
    for (int qq = 0; qq < 4; ++qq)
      buf[i][qq] = *(const float4*)(vz + i * 16 + qq * 4);

  float cur = 0.f, volt = 0.f;
  int c = 0;
#pragma unroll
  for (int tc = 0; tc < 16; ++tc) {
    float zv[16];
    *(float4*)&zv[0]  = buf[tc & 3][0];
    *(float4*)&zv[4]  = buf[tc & 3][1];
    *(float4*)&zv[8]  = buf[tc & 3][2];
    *(float4*)&zv[12] = buf[tc & 3][3];
    if (tc < 12) {
#pragma unroll
      for (int qq = 0; qq < 4; ++qq)
        buf[tc & 3][qq] = *(const float4*)(vz + (tc + 4) * 16 + qq * 4);
    }
    float vv[16], sv[16];
    unsigned short sb[16];
#pragma unroll
    for (int j = 0; j < 16; ++j) {
      cur = CD * cur + zv[j];
      volt = VD * volt + cur;
      vv[j] = volt;  // pre-reset voltage
      const bool spk = volt >= 1.25f;
      sv[j] = spk ? 1.0f : 0.0f;
      sb[j] = spk ? 0x3F80 : 0;  // bf16(1.0) / bf16(0.0)
      c += spk ? 1 : 0;
      volt = spk ? 0.f : volt;
    }
    float4 o;
    o = {vv[0], vv[1], vv[2], vv[3]};     *(float4*)(vz + tc * 16 + 0) = o;
    o = {vv[4], vv[5], vv[6], vv[7]};     *(float4*)(vz + tc * 16 + 4) = o;
    o = {vv[8], vv[9], vv[10], vv[11]};   *(float4*)(vz + tc * 16 + 8) = o;
    o = {vv[12], vv[13], vv[14], vv[15]}; *(float4*)(vz + tc * 16 + 12) = o;
    o = {sv[0], sv[1], sv[2], sv[3]};     *(float4*)(sp + tc * 16 + 0) = o;
    o = {sv[4], sv[5], sv[6], sv[7]};     *(float4*)(sp + tc * 16 + 4) = o;
    o = {sv[8], sv[9], sv[10], sv[11]};   *(float4*)(sp + tc * 16 + 8) = o;
    o = {sv[12], sv[13], sv[14], sv[15]}; *(float4*)(sp + tc * 16 + 12) = o;
    if (st) {
#pragma unroll
      for (int j = 0; j < 16; ++j)
        st[(size_t)(tc * 16 + j) * 1024] = sb[j];
    }
  }
#pragma unroll
  for (int off = 32; off > 0; off >>= 1) c += __shfl_down(c, off);
  if (threadIdx.x == 0) atomicAdd(cnt, c);
}

__global__ void finalize_kernel(const int* __restrict__ cnt, float* __restrict__ c) {
  if (threadIdx.x == 0) {
    c[0] = (float)cnt[0] * (1.0f / 8388608.0f);
    c[1] = (float)cnt[1] * (1.0f / 8388608.0f);
  }
}

// ================= fallback path (round-1 f32 kernels) =================

__global__ __launch_bounds__(256) void zero_r_kernel(float* __restrict__ r,
                                                     int* __restrict__ cnt) {
  int i = blockIdx.x * 256 + threadIdx.x;
  float4 z{0.f, 0.f, 0.f, 0.f};
  *(float4*)&r[(size_t)i * 4] = z;
  if (i == 0) { cnt[0] = 0; cnt[1] = 0; }
}

__global__ __launch_bounds__(256) void gemm_f32(
    const float* __restrict__ W, const float* __restrict__ X,
    float* __restrict__ Z, int M, int K) {
  const int T = 256;
  const int tt0 = blockIdx.x * 64;
  const int m0 = blockIdx.y * 128;
  const int b = blockIdx.z;
  const float* __restrict__ Xb = X + (size_t)b * K * T;
  float* __restrict__ Zb = Z + (size_t)b * M * T;
  __shared__ float Ws[16][132];
  __shared__ float Xs[16][68];
  const int tid = threadIdx.x;
  const int tx = tid & 15, ty = tid >> 4;
  const int ah = tid >> 1, ac = (tid & 1) * 8;
  const int bf = tid >> 4, btq = (tid & 15) * 4;
  float acc[8][4];
#pragma unroll
  for (int i = 0; i < 8; ++i)
#pragma unroll
    for (int j = 0; j < 4; ++j) acc[i][j] = 0.f;
  const float* wp = &W[(size_t)(m0 + ah) * K + ac];
  const float* xp = &Xb[(size_t)bf * T + tt0 + btq];
  for (int k0 = 0; k0 < K; k0 += 16) {
    float4 wa0 = *(const float4*)(wp + k0);
    float4 wa1 = *(const float4*)(wp + k0 + 4);
    float4 xv = *(const float4*)(xp + (size_t)k0 * T);
    __syncthreads();
    Ws[ac + 0][ah] = wa0.x; Ws[ac + 1][ah] = wa0.y;
    Ws[ac + 2][ah] = wa0.z; Ws[ac + 3][ah] = wa0.w;
    Ws[ac + 4][ah] = wa1.x; Ws[ac + 5][ah] = wa1.y;
    Ws[ac + 6][ah] = wa1.z; Ws[ac + 7][ah] = wa1.w;
    *(float4*)&Xs[bf][btq] = xv;
    __syncthreads();
#pragma unroll
    for (int f = 0; f < 16; ++f) {
      float4 a0 = *(const float4*)&Ws[f][ty * 8];
      float4 a1 = *(const float4*)&Ws[f][ty * 8 + 4];
      float4 xr = *(const float4*)&Xs[f][tx * 4];
      float av[8] = {a0.x, a0.y, a0.z, a0.w, a1.x, a1.y, a1.z, a1.w};
      float xw[4] = {xr.x, xr.y, xr.z, xr.w};
#pragma unroll
      for (int i = 0; i < 8; ++i)
#pragma unroll
        for (int j = 0; j < 4; ++j) acc[i][j] = fmaf(av[i], xw[j], acc[i][j]);
    }
  }
#pragma unroll
  for (int i = 0; i < 8; ++i) {
    float4 o{acc[i][0], acc[i][1], acc[i][2], acc[i][3]};
    *(float4*)&Zb[(size_t)(m0 + ty * 8 + i) * T + tt0 + tx * 4] = o;
  }
}

__global__ __launch_bounds__(256) void readout_kernel(
    const float* __restrict__ R1, const float* __restrict__ R2,
    const float* __restrict__ S1, const float* __restrict__ S2,
    float* __restrict__ O1, float* __restrict__ O2) {
  const int T = 256, K = 1024;
  const int tt0 = blockIdx.x * 64;
  const int kbeg = blockIdx.y * 256;
  const int zz = blockIdx.z;
  const int b = zz & 31;
  const float* __restrict__ R = (zz < 32) ? R1 : R2;
  const float* __restrict__ Sb = ((zz < 32) ? S1 : S2) + (size_t)b * K * T;
  float* __restrict__ Ob = ((zz < 32) ? O1 : O2) + (size_t)b * 128 * T;
  __shared__ float Ws[16][132];
  __shared__ float Xs[16][68];
  const int tid = threadIdx.x;
  const int tx = tid & 15, ty = tid >> 4;
  const int ah = tid >> 1, ac = (tid & 1) * 8;
  const int bf = tid >> 4, btq = (tid & 15) * 4;
  float acc[8][4];
#pragma unroll
  for (int i = 0; i < 8; ++i)
#pragma unroll
    for (int j = 0; j < 4; ++j) acc[i][j] = 0.f;
  const float* wp = &R[(size_t)ah * K + ac];
  const float* xp = &Sb[(size_t)bf * T + tt0 + btq];
  for (int k0 = kbeg; k0 < kbeg + 256; k0 += 16) {
    float4 wa0 = *(const float4*)(wp + k0);
    float4 wa1 = *(const float4*)(wp + k0 + 4);
    float4 xv = *(const float4*)(xp + (size_t)k0 * T);
    __syncthreads();
    Ws[ac + 0][ah] = wa0.x; Ws[ac + 1][ah] = wa0.y;
    Ws[ac + 2][ah] = wa0.z; Ws[ac + 3][ah] = wa0.w;
    Ws[ac + 4][ah] = wa1.x; Ws[ac + 5][ah] = wa1.y;
    Ws[ac + 6][ah] = wa1.z; Ws[ac + 7][ah] = wa1.w;
    *(float4*)&Xs[bf][btq] = xv;
    __syncthreads();
#pragma unroll
    for (int f = 0; f < 16; ++f) {
      float4 a0 = *(const float4*)&Ws[f][ty * 8];
      float4 a1 = *(const float4*)&Ws[f][ty * 8 + 4];
      float4 xr = *(const float4*)&Xs[f][tx * 4];
      float av[8] = {a0.x, a0.y, a0.z, a0.w, a1.x, a1.y, a1.z, a1.w};
      float xw[4] = {xr.x, xr.y, xr.z, xr.w};
#pragma unroll
      for (int i = 0; i < 8; ++i)
#pragma unroll
        for (int j = 0; j < 4; ++j) acc[i][j] = fmaf(av[i], xw[j], acc[i][j]);
    }
  }
#pragma unroll
  for (int i = 0; i < 8; ++i)
#pragma unroll
    for (int j = 0; j < 4; ++j)
      atomicAdd(&Ob[(size_t)(ty * 8 + i) * T + tt0 + tx * 4 + j], acc[i][j]);
}

// ================= launch =================
extern "C" void kernel_launch(void* const* d_in, const int* in_sizes, int n_in,
                              void* d_out, int out_size, void* d_ws, size_t ws_size,
                              hipStream_t stream) {
  const float* spike = (const float*)d_in[0];
  const float* W1 = (const float*)d_in[1];
  const float* W2 = (const float*)d_in[2];
  const float* R1 = (const float*)d_in[3];
  const float* R2 = (const float*)d_in[4];

  float* out = (float*)d_out;
  float* s1 = out;
  float* s2 = out + S_SZ;
  float* r1 = out + 2 * S_SZ;
  float* r2 = out + 2 * S_SZ + R_SZ;
  float* v1 = out + 2 * S_SZ + 2 * R_SZ;  // z1 then v1, in place
  float* v2 = out + 2 * S_SZ + 2 * R_SZ + S_SZ;
  float* cc = out + 4 * S_SZ + 2 * R_SZ;

  int* cnt = (int*)d_ws;
  unsigned short* w1s = (unsigned short*)((char*)d_ws + 64);
  unsigned short* w2s = w1s + 3 * 524288;
  unsigned short* r1s = w2s + 3 * 1048576;
  unsigned short* r2s = r1s + 3 * 131072;
  unsigned short* xT  = r2s + 3 * 131072;
  unsigned short* s1T = xT + 4194304;
  unsigned short* s2T = s1T + 8388608;
  const size_t WS_NEED = 53000000;

  if (ws_size >= WS_NEED) {
    split_all_kernel<<<dim3(4096, 4), 256, 0, stream>>>(W1, W2, R1, R2, w1s, w2s,
                                                        r1s, r2s, cnt);
    tcvt_kernel<<<dim3(8, 4, 32), 256, 0, stream>>>(spike, xT, 512);
    gemm_mfma<<<dim3(4, 8, 16), 256, 0, stream>>>(w1s, xT, v1, 1024, 512);
    scan_kernel<<<512, 64, 0, stream>>>(v1, s1, s1T, cnt + 0);
    gemm_mfma<<<dim3(4, 8, 16), 256, 0, stream>>>(w2s, s1T, v2, 1024, 1024);
    scan_kernel<<<512, 64, 0, stream>>>(v2, s2, s2T, cnt + 1);
    readout_mfma<<<dim3(4, 2, 32), 256, 0, stream>>>(r1s, r2s, s1T, s2T, r1, r2,
                                                     cnt, cc);
  } else {
    zero_r_kernel<<<2048, 256, 0, stream>>>(r1, cnt);
    gemm_f32<<<dim3(4, 8, 32), 256, 0, stream>>>(W1, spike, v1, 1024, 512);
    scan_kernel<<<512, 64, 0, stream>>>(v1, s1, nullptr, cnt + 0);
    gemm_f32<<<dim3(4, 8, 32), 256, 0, stream>>>(W2, s1, v2, 1024, 1024);
    scan_kernel<<<512, 64, 0, stream>>>(v2, s2, nullptr, cnt + 1);
    readout_kernel<<<dim3(4, 4, 64), 256, 0, stream>>>(R1, R2, s1, s2, r1, r2);
    finalize_kernel<<<1, 1, 0, stream>>>(cnt, cc);
  }
}